// Round 4
// baseline (81.146 us; speedup 1.0000x reference)
//
#include <hip/hip_runtime.h>

#define NN 512
#define GRP 8

// ws layout: [0,16) bytes = hdr { f32 acc, u32 counter } ; [16, 16 + nsplit*1MB) = sim planes

__global__ __launch_bounds__(256) void gemm_sym(const float* __restrict__ B,
                                                float* __restrict__ sim,
                                                float* __restrict__ hdr,
                                                int kspan) {
  __shared__ float At[32][34];  // [k][row], stride 34 keeps b64 reads 8B-aligned
  __shared__ float Bt[32][34];
  const int tid = threadIdx.x;
  if (blockIdx.x == 0 && blockIdx.y == 0 && blockIdx.z == 0 && tid == 0) {
    hdr[0] = 0.0f;
    ((unsigned int*)hdr)[1] = 0u;
  }
  const int bx = blockIdx.x, by = blockIdx.y, z = blockIdx.z;
  const int kb = z * kspan, kend = kb + kspan;
  const int row = tid >> 3;        // 0..31
  const int kq  = (tid & 7) << 2;  // 0,4,...,28
  const int ty = tid >> 4, tx = tid & 15;
  float c00 = 0.f, c01 = 0.f, c10 = 0.f, c11 = 0.f;
  const float* Arow = B + (by * 32 + row) * NN;
  const float* Brow = B + (bx * 32 + row) * NN;
  // software prefetch: chunk 0 loaded before the loop; chunk k+1 issued
  // right after the barrier so ~200cy L2 latency hides under the FMA loop
  float4 av = *(const float4*)(Arow + kb + kq);
  float4 bv = *(const float4*)(Brow + kb + kq);
  for (int kc = kb; kc < kend; kc += 32) {
    __syncthreads();  // protect LDS from previous iteration's readers
    At[kq + 0][row] = av.x; At[kq + 1][row] = av.y;
    At[kq + 2][row] = av.z; At[kq + 3][row] = av.w;
    Bt[kq + 0][row] = bv.x; Bt[kq + 1][row] = bv.y;
    Bt[kq + 2][row] = bv.z; Bt[kq + 3][row] = bv.w;
    __syncthreads();
    if (kc + 32 < kend) {
      av = *(const float4*)(Arow + kc + 32 + kq);
      bv = *(const float4*)(Brow + kc + 32 + kq);
    }
#pragma unroll
    for (int kk = 0; kk < 32; ++kk) {
      const float2 a = *(const float2*)&At[kk][2 * ty];
      const float2 b = *(const float2*)&Bt[kk][2 * tx];
      c00 = fmaf(a.x, b.x, c00);
      c01 = fmaf(a.x, b.y, c01);
      c10 = fmaf(a.y, b.x, c10);
      c11 = fmaf(a.y, b.y, c11);
    }
  }
  float* C = sim + (size_t)z * NN * NN + (by * 32 + 2 * ty) * NN + (bx * 32 + 2 * tx);
  C[0] = c00; C[1] = c01; C[NN] = c10; C[NN + 1] = c11;
}

__global__ __launch_bounds__(256) void rank_loss(const float* __restrict__ sim,
                                                 float* __restrict__ hdr,
                                                 float* __restrict__ out,
                                                 int nplanes) {
  __shared__ float srow[NN];
  __shared__ float spart[4][8];
  const int b = blockIdx.x;
  const int tid = threadIdx.x;
  const int g0 = b & ~(GRP - 1);
  {
    float2 v = *(const float2*)(sim + b * NN + tid * 2);
    for (int p = 1; p < nplanes; ++p) {
      float2 w = *(const float2*)(sim + (size_t)p * NN * NN + b * NN + tid * 2);
      v.x += w.x; v.y += w.y;
    }
    *(float2*)&srow[tid * 2] = v;
  }
  __syncthreads();
  float vj[GRP];
#pragma unroll
  for (int j = 0; j < GRP; ++j) vj[j] = srow[g0 + j];
  float part[GRP];
#pragma unroll
  for (int j = 0; j < GRP; ++j) part[j] = 0.f;
#pragma unroll
  for (int t = 0; t < 2; ++t) {
    const int k = tid + t * 256;
    const float vk = srow[k];
    const bool masked = (k >= g0) && (k < g0 + GRP);
#pragma unroll
    for (int j = 0; j < GRP; ++j) {
      // expo = clip((sim[b,j]-sim[b,k])/0.01, -50, 50); term = 1/(1+exp(expo))
      float d = (vj[j] - vk) * 100.0f;
      d = fminf(fmaxf(d, -50.0f), 50.0f);
      float s = 1.0f / (1.0f + __expf(d));
      if (!masked) part[j] += s;
    }
  }
  // wave-level butterfly reduce each of the 8 partials
#pragma unroll
  for (int j = 0; j < GRP; ++j) {
    float x = part[j];
#pragma unroll
    for (int off = 32; off > 0; off >>= 1) x += __shfl_xor(x, off);
    part[j] = x;
  }
  const int wave = tid >> 6, lane = tid & 63;
  if (lane == 0) {
#pragma unroll
    for (int j = 0; j < GRP; ++j) spart[wave][j] = part[j];
  }
  __syncthreads();
  if (tid < 64) {
    float term = 0.0f;
    if (tid < 8) {
      float S = spart[0][tid] + spart[1][tid] + spart[2][tid] + spart[3][tid];
      float t1 = 1.0f + S;
      float t2 = t1 * t1;
      term = 1.0f / (t2 * t2);  // 1/(1+S)^4
    }
    term += __shfl_xor(term, 1);
    term += __shfl_xor(term, 2);
    term += __shfl_xor(term, 4);
    if (tid == 0) {
      atomicAdd(hdr, term);
      __threadfence();
      unsigned int old = atomicAdd(((unsigned int*)hdr) + 1, 1u);
      if (old == gridDim.x - 1) {  // last block: finalize
        __threadfence();
        float total = atomicAdd(hdr, 0.0f);  // coherent read
        out[0] = 1.0f - total * (1.0f / 4096.0f);
      }
    }
  }
}

extern "C" void kernel_launch(void* const* d_in, const int* in_sizes, int n_in,
                              void* d_out, int out_size, void* d_ws, size_t ws_size,
                              hipStream_t stream) {
  const float* batch = (const float*)d_in[0];
  float* hdr = (float*)d_ws;
  float* sim = (float*)((char*)d_ws + 16);
  float* out = (float*)d_out;
  // K-split: more co-resident blocks/CU for DS/FMA issue overlap; LDS-traffic
  // floor is split-invariant, this buys latency tolerance + smaller tail.
  const size_t plane = (size_t)NN * NN * sizeof(float);
  int nsplit = 1;
  if (ws_size >= 16 + 4 * plane) nsplit = 4;
  else if (ws_size >= 16 + 2 * plane) nsplit = 2;
  dim3 g1(16, 16, nsplit);
  gemm_sym<<<g1, 256, 0, stream>>>(batch, sim, hdr, NN / nsplit);
  rank_loss<<<NN, 256, 0, stream>>>(sim, hdr, out, nsplit);
}

// Round 6
// 80.023 us; speedup vs baseline: 1.0140x; 1.0140x over previous
//
#include <hip/hip_runtime.h>

#define NN 512
#define GRP 8
#define TILE 64
#define KCH 32
#define LDST 68  // padded k-major stride: float4 reads stay 16B-aligned, writes 4-way worst

// ws layout: [0,16) bytes = hdr { f32 acc, u32 counter } ; [16, 16 + nsplit*1MB) = sim planes

__global__ __launch_bounds__(256) void gemm_sym(const float* __restrict__ B,
                                                float* __restrict__ sim,
                                                float* __restrict__ hdr,
                                                int kspan) {
  __shared__ float At[KCH][LDST];  // [k][row] so fragment reads are contiguous float4
  __shared__ float Bt[KCH][LDST];
  const int tid = threadIdx.x;
  if (blockIdx.x == 0 && blockIdx.y == 0 && blockIdx.z == 0 && tid == 0) {
    hdr[0] = 0.0f;
    ((unsigned int*)hdr)[1] = 0u;
  }
  const int bx = blockIdx.x, by = blockIdx.y, z = blockIdx.z;
  const int kb = z * kspan, kend = kb + kspan;
  const int r  = tid >> 2;          // 0..63: staging row within tile
  const int kq = (tid & 3) << 3;    // 0,8,16,24: staging k-offset (8 floats each)
  const int ty = tid >> 4, tx = tid & 15;
  float acc[4][4] = {};
  const float* Arow = B + (by * TILE + r) * NN + kq;
  const float* Brow = B + (bx * TILE + r) * NN + kq;
  // software prefetch: chunk 0 before the loop; chunk k+1 issued right after
  // the barrier so ~200cy L2 latency hides under the 32-step FMA loop
  float4 a0 = *(const float4*)(Arow + kb);
  float4 a1 = *(const float4*)(Arow + kb + 4);
  float4 b0 = *(const float4*)(Brow + kb);
  float4 b1 = *(const float4*)(Brow + kb + 4);
  for (int kc = kb; kc < kend; kc += KCH) {
    __syncthreads();  // protect LDS from previous iteration's readers
    At[kq + 0][r] = a0.x; At[kq + 1][r] = a0.y; At[kq + 2][r] = a0.z; At[kq + 3][r] = a0.w;
    At[kq + 4][r] = a1.x; At[kq + 5][r] = a1.y; At[kq + 6][r] = a1.z; At[kq + 7][r] = a1.w;
    Bt[kq + 0][r] = b0.x; Bt[kq + 1][r] = b0.y; Bt[kq + 2][r] = b0.z; Bt[kq + 3][r] = b0.w;
    Bt[kq + 4][r] = b1.x; Bt[kq + 5][r] = b1.y; Bt[kq + 6][r] = b1.z; Bt[kq + 7][r] = b1.w;
    __syncthreads();
    if (kc + KCH < kend) {
      a0 = *(const float4*)(Arow + kc + KCH);
      a1 = *(const float4*)(Arow + kc + KCH + 4);
      b0 = *(const float4*)(Brow + kc + KCH);
      b1 = *(const float4*)(Brow + kc + KCH + 4);
    }
#pragma unroll
    for (int kk = 0; kk < KCH; ++kk) {
      const float4 a4 = *(const float4*)&At[kk][4 * ty];
      const float4 b4 = *(const float4*)&Bt[kk][4 * tx];
      const float ar[4] = {a4.x, a4.y, a4.z, a4.w};
      const float br[4] = {b4.x, b4.y, b4.z, b4.w};
#pragma unroll
      for (int i = 0; i < 4; ++i)
#pragma unroll
        for (int j = 0; j < 4; ++j) acc[i][j] = fmaf(ar[i], br[j], acc[i][j]);
    }
  }
  float* C = sim + (size_t)z * NN * NN + (by * TILE + 4 * ty) * NN + bx * TILE + 4 * tx;
#pragma unroll
  for (int i = 0; i < 4; ++i) {
    float4 v = {acc[i][0], acc[i][1], acc[i][2], acc[i][3]};
    *(float4*)(C + i * NN) = v;
  }
}

__global__ __launch_bounds__(256) void rank_loss(const float* __restrict__ sim,
                                                 float* __restrict__ hdr,
                                                 float* __restrict__ out,
                                                 int nplanes) {
  __shared__ float srow[NN];
  __shared__ float spart[4][8];
  const int b = blockIdx.x;
  const int tid = threadIdx.x;
  const int g0 = b & ~(GRP - 1);
  {
    float2 v = *(const float2*)(sim + b * NN + tid * 2);
    for (int p = 1; p < nplanes; ++p) {
      float2 w = *(const float2*)(sim + (size_t)p * NN * NN + b * NN + tid * 2);
      v.x += w.x; v.y += w.y;
    }
    *(float2*)&srow[tid * 2] = v;
  }
  __syncthreads();
  float vj[GRP];
#pragma unroll
  for (int j = 0; j < GRP; ++j) vj[j] = srow[g0 + j];
  float part[GRP];
#pragma unroll
  for (int j = 0; j < GRP; ++j) part[j] = 0.f;
#pragma unroll
  for (int t = 0; t < 2; ++t) {
    const int k = tid + t * 256;
    const float vk = srow[k];
    const bool masked = (k >= g0) && (k < g0 + GRP);
#pragma unroll
    for (int j = 0; j < GRP; ++j) {
      // expo = clip((sim[b,j]-sim[b,k])/0.01, -50, 50); term = 1/(1+exp(expo))
      float d = (vj[j] - vk) * 100.0f;
      d = fminf(fmaxf(d, -50.0f), 50.0f);
      float s = 1.0f / (1.0f + __expf(d));
      if (!masked) part[j] += s;
    }
  }
  // wave-level butterfly reduce each of the 8 partials
#pragma unroll
  for (int j = 0; j < GRP; ++j) {
    float x = part[j];
#pragma unroll
    for (int off = 32; off > 0; off >>= 1) x += __shfl_xor(x, off);
    part[j] = x;
  }
  const int wave = tid >> 6, lane = tid & 63;
  if (lane == 0) {
#pragma unroll
    for (int j = 0; j < GRP; ++j) spart[wave][j] = part[j];
  }
  __syncthreads();
  if (tid < 64) {
    float term = 0.0f;
    if (tid < 8) {
      float S = spart[0][tid] + spart[1][tid] + spart[2][tid] + spart[3][tid];
      float t1 = 1.0f + S;
      float t2 = t1 * t1;
      term = 1.0f / (t2 * t2);  // 1/(1+S)^4
    }
    term += __shfl_xor(term, 1);
    term += __shfl_xor(term, 2);
    term += __shfl_xor(term, 4);
    if (tid == 0) {
      atomicAdd(hdr, term);
      __threadfence();
      unsigned int old = atomicAdd(((unsigned int*)hdr) + 1, 1u);
      if (old == gridDim.x - 1) {  // last block: finalize
        __threadfence();
        float total = atomicAdd(hdr, 0.0f);  // coherent read
        out[0] = 1.0f - total * (1.0f / 4096.0f);
      }
    }
  }
}

extern "C" void kernel_launch(void* const* d_in, const int* in_sizes, int n_in,
                              void* d_out, int out_size, void* d_ws, size_t ws_size,
                              hipStream_t stream) {
  const float* batch = (const float*)d_in[0];
  float* hdr = (float*)d_ws;
  float* sim = (float*)((char*)d_ws + 16);
  float* out = (float*)d_out;
  // 64x64 tiles, 4x4 frags (FMA-bound). K-split=8 -> 512 blocks = 2/CU = 2
  // waves/SIMD so DS-read and FMA issue overlap across waves.
  const size_t plane = (size_t)NN * NN * sizeof(float);
  int nsplit = 1;
  if (ws_size >= 16 + 8 * plane) nsplit = 8;
  else if (ws_size >= 16 + 4 * plane) nsplit = 4;
  else if (ws_size >= 16 + 2 * plane) nsplit = 2;
  dim3 g1(NN / TILE, NN / TILE, nsplit);
  gemm_sym<<<g1, 256, 0, stream>>>(batch, sim, hdr, NN / nsplit);
  rank_loss<<<NN, 256, 0, stream>>>(sim, hdr, out, nsplit);
}